// Round 5
// baseline (127.789 us; speedup 1.0000x reference)
//
#include <hip/hip_runtime.h>

#define B_   8
#define N_   512
#define IND  256
#define H_   4
#define PH   32
#define OD   128   // H_*PH
#define TI   4     // targets per block (attn)

typedef float v2f __attribute__((ext_vector_type(2)));

// leaky 0.4 * log2(e), and 0.6 * log2(e): logits in log2 domain -> v_exp_f32.
#define ATT_SCALE 0.5770780163555854f
#define DLR_SCALE 0.8656170245333781f

template <int PAT>
__device__ __forceinline__ float dpp_add(float x) {
    int yi = __builtin_amdgcn_mov_dpp(__float_as_int(x), PAT, 0xF, 0xF, true);
    return x + __int_as_float(yi);
}

__device__ __forceinline__ float fast_exp2(float x) {
#if __has_builtin(__builtin_amdgcn_exp2f)
    return __builtin_amdgcn_exp2f(x);
#else
    return exp2f(x);
#endif
}

// Packed fp32 FMA: d += a*b on both halves, ONE VOP3P instruction.
__device__ __forceinline__ void pk_fma(v2f& d, v2f a, v2f b) {
    asm("v_pk_fma_f32 %0, %1, %2, %0" : "+v"(d) : "v"(a), "v"(b));
}

// ---------------------------------------------------------------------------
// Kernel 1 v6: xl = x@Wl + bl ; xr = x@Wr + br  plus pre-scaled rank-1 parts.
// r4 post-mortem: v5's regression (31->41us) was W redundancy (4x/block =
// 512 MB L2 ~ 15us floor) + no prefetch. v6 makes W redundancy EXACTLY 1x:
//   512 thr = og(32 col-quads) x ks(8 K-slices of 32) x which(2)
//   thread = 8 rows x 4 cols x 32 k -> each W element read by ONE thread.
//   W traffic 256 KB/block x 512 = 128 MB L2 (~4us), vs v4 256MB / v5 512MB.
// W keeps v4's proven 1-deep parity prefetch (static idx, no copies).
// x rows come from LDS (wave-broadcast, free). K-combine over 8 ks-slices
// via LDS stride-33 (<=2-way banks, free); final sum distributed over all
// 512 threads -> coalesced float4 stores.
// ---------------------------------------------------------------------------
__global__ __launch_bounds__(512, 2) void proj_kernel(
    const float* __restrict__ x,
    const float* __restrict__ Wl, const float* __restrict__ bl,
    const float* __restrict__ Wr, const float* __restrict__ br,
    const float* __restrict__ att,
    float* __restrict__ xl, float* __restrict__ xr,
    float* __restrict__ dl, float* __restrict__ dr)
{
    __shared__ float xs[8 * IND];        // 8 KB
    __shared__ float comb[8][64][33];    // 67.6 KB; (pid*33+i)%32 -> no conflict

    const int t = threadIdx.x;
    const int row0 = blockIdx.x * 8;

    ((float4*)xs)[t] = ((const float4*)(x + (size_t)row0 * IND))[t];
    __syncthreads();

    const int og    = t & 31;        // col quad: cols og*4 .. og*4+3
    const int ks    = (t >> 5) & 7;  // K slice: k0 = ks*32
    const int which = t >> 8;        // 0: Wl->xl/dl, 1: Wr->xr/dr
    const int o0 = og * 4;
    const int k0 = ks * 32;
    const float* W = (which ? Wr : Wl) + (size_t)k0 * OD + o0;

    float acc[8][4];
    #pragma unroll
    for (int r = 0; r < 8; ++r)
        #pragma unroll
        for (int c = 0; c < 4; ++c) acc[r][c] = 0.f;

    float4 wb[2][4];
    #pragma unroll
    for (int kk = 0; kk < 4; ++kk)
        wb[0][kk] = *(const float4*)(W + (size_t)kk * OD);

    #pragma unroll 2
    for (int s = 0; s < 8; ++s) {        // 8 chunks of 4 k (K=32 per thread)
        const int cur = s & 1, nxt = cur ^ 1;
        if (s < 7) {
            const float* Wq = W + (size_t)((s + 1) * 4) * OD;
            #pragma unroll
            for (int kk = 0; kk < 4; ++kk)
                wb[nxt][kk] = *(const float4*)(Wq + (size_t)kk * OD);
        }
        float4 xv[8];
        #pragma unroll
        for (int r = 0; r < 8; ++r)
            xv[r] = *(const float4*)(&xs[r * IND + k0 + s * 4]);
        #pragma unroll
        for (int kk = 0; kk < 4; ++kk) {
            #pragma unroll
            for (int r = 0; r < 8; ++r) {
                const float xk = (kk == 0) ? xv[r].x : (kk == 1) ? xv[r].y
                               : (kk == 2) ? xv[r].z : xv[r].w;
                acc[r][0] = fmaf(xk, wb[cur][kk].x, acc[r][0]);
                acc[r][1] = fmaf(xk, wb[cur][kk].y, acc[r][1]);
                acc[r][2] = fmaf(xk, wb[cur][kk].z, acc[r][2]);
                acc[r][3] = fmaf(xk, wb[cur][kk].w, acc[r][3]);
            }
        }
    }

    // stage all 8 K-slice partials (scalar writes; (pid*33+i)%32 = pid+i)
    const int pid = og | (which << 5);   // 0..63
    #pragma unroll
    for (int i = 0; i < 32; ++i)
        comb[ks][pid][i] = acc[i >> 2][i & 3];
    __syncthreads();

    // final: thread t -> which' = t>>8, r' = (t>>5)&7, og' = t&31
    const int ogf = t & 31;
    const int rf  = (t >> 5) & 7;
    const int whf = t >> 8;
    const int pidf = ogf | (whf << 5);
    const float* bb = whf ? br : bl;
    float* dst = whf ? xr : xl;
    float* dp  = whf ? dr : dl;
    float4 bv = *(const float4*)(bb + ogf * 4);
    float4 av = *(const float4*)(att + ogf * 4);
    const float bvf[4] = {bv.x, bv.y, bv.z, bv.w};
    const float avf[4] = {av.x, av.y, av.z, av.w};
    float y[4];
    #pragma unroll
    for (int c = 0; c < 4; ++c) {
        const int idx = rf * 4 + c;
        float s01 = comb[0][pidf][idx] + comb[1][pidf][idx];
        float s23 = comb[2][pidf][idx] + comb[3][pidf][idx];
        float s45 = comb[4][pidf][idx] + comb[5][pidf][idx];
        float s67 = comb[6][pidf][idx] + comb[7][pidf][idx];
        y[c] = ((s01 + s23) + (s45 + s67)) + bvf[c];
    }
    *(float4*)(&dst[(size_t)(row0 + rf) * OD + ogf * 4]) =
        make_float4(y[0], y[1], y[2], y[3]);
    // rank-1 part: dl/dr[n,h] = 0.6*log2e * sum_c att[h,c]*y[c]
    float dc = fmaf(avf[0], y[0], fmaf(avf[1], y[1],
               fmaf(avf[2], y[2], avf[3] * y[3])));
    dc += __shfl_xor(dc, 1);
    dc += __shfl_xor(dc, 2);
    dc += __shfl_xor(dc, 4);   // sums the 8 og-lanes of one head
    if ((ogf & 7) == 0)
        dp[(size_t)(row0 + rf) * H_ + (ogf >> 3)] = DLR_SCALE * dc;
}

// ---------------------------------------------------------------------------
// Kernel 2 v6: masked-softmax attention aggregate, TI=4 (proven best).
// r4 counters: VGPR=68 -- ONE reg over the 64 occupancy cliff (m69) -> only
// 4 waves/SIMD; LDS epilogue (33KB) pinned 4 blocks/CU + 2 barriers.
// v6 shaves below the cliff and drops LDS entirely:
//   * manual j-pipeline removed (~13 live regs); 8 waves/SIMD TLP hides the
//     L2 latency the pipeline was hiding.
//   * epilogue = 4-step __shfl_xor butterfly over the js lane-bits (masks
//     4/8/16/32; cq bits 0-1 preserved) -> all lanes hold full j-sums; 8
//     lanes/wave then write one float4 each. LDS -> 0, no barriers.
//   * __launch_bounds__(256,4) pins VGPR<=64 -> 8 waves/SIMD.
// XCD<->batch swizzle kept (FETCH 42->6 MB measured r3/r4).
// ---------------------------------------------------------------------------
__global__ __launch_bounds__(256, 4) void attn_kernel(
    const int* __restrict__ adj, const float* __restrict__ att,
    const float* __restrict__ bias,
    const float* __restrict__ xl, const float* __restrict__ xr,
    const float* __restrict__ dl, const float* __restrict__ dr,
    float* __restrict__ out)
{
    const int t = threadIdx.x;
    const int bid = (blockIdx.x & 7) * 128 + (blockIdx.x >> 3);
    const int b  = bid >> 7;
    const int i0 = (bid & 127) * TI;
    const int cq = t & 3;
    const int h  = t >> 6;
    const int js = (t >> 2) & 15;
    const int cbase = h * PH + cq * 8;

    // preload att (pre-scaled by 0.4*log2e) and xr fragments for all 4 targets
    float atS[8];
    {
        const float* ap = att + cbase;
        float4 a0 = *(const float4*)(ap);
        float4 a1 = *(const float4*)(ap + 4);
        atS[0] = ATT_SCALE * a0.x; atS[1] = ATT_SCALE * a0.y;
        atS[2] = ATT_SCALE * a0.z; atS[3] = ATT_SCALE * a0.w;
        atS[4] = ATT_SCALE * a1.x; atS[5] = ATT_SCALE * a1.y;
        atS[6] = ATT_SCALE * a1.z; atS[7] = ATT_SCALE * a1.w;
    }
    float xrS[TI][8];
    float drv[TI];
    #pragma unroll
    for (int il = 0; il < TI; ++il) {
        const float* xp = xr + ((size_t)(b * N_ + i0 + il)) * OD + cbase;
        float4 r0 = *(const float4*)(xp);
        float4 r1 = *(const float4*)(xp + 4);
        xrS[il][0] = r0.x; xrS[il][1] = r0.y; xrS[il][2] = r0.z; xrS[il][3] = r0.w;
        xrS[il][4] = r1.x; xrS[il][5] = r1.y; xrS[il][6] = r1.z; xrS[il][7] = r1.w;
        drv[il] = dr[((size_t)(b * N_ + i0 + il)) * H_ + h];  // pre-scaled
    }

    v2f acc[TI][4];
    float sumw[TI];
    #pragma unroll
    for (int il = 0; il < TI; ++il) {
        sumw[il] = 0.f;
        #pragma unroll
        for (int m = 0; m < 4; ++m) acc[il][m] = (v2f){0.f, 0.f};
    }

    // j-loop: j = u*16 + js, u = 0..31 (no manual pipeline -- TLP covers it)
    const float* xlp = xl + ((size_t)(b * N_ + js)) * OD + cbase;
    const int*   ajp = adj + ((size_t)(b * N_ + js)) * N_ + i0;
    const float* dlp = dl + ((size_t)(b * N_ + js)) * H_ + h;

    #pragma unroll 2
    for (int u = 0; u < 32; ++u) {
        float4 wa = *(const float4*)(xlp);
        float4 wb = *(const float4*)(xlp + 4);
        int4   wm = *(const int4*)(ajp);
        float  wd = *dlp;
        xlp += 16 * OD; ajp += 16 * N_; dlp += 16 * H_;

        const int j = u * 16 + js;
        v2f p0 = (v2f){wa.x, wa.y}, p1 = (v2f){wa.z, wa.w};
        v2f p2 = (v2f){wb.x, wb.y}, p3 = (v2f){wb.z, wb.w};
        int wmv[TI] = {wm.x, wm.y, wm.z, wm.w};
        #pragma unroll
        for (int il = 0; il < TI; ++il) {
            float s, e2a = 0.f, e2b = 0.f;
            s = xrS[il][0] + wa.x; e2a = fmaf(atS[0], __builtin_fabsf(s), e2a);
            s = xrS[il][1] + wa.y; e2b = fmaf(atS[1], __builtin_fabsf(s), e2b);
            s = xrS[il][2] + wa.z; e2a = fmaf(atS[2], __builtin_fabsf(s), e2a);
            s = xrS[il][3] + wa.w; e2b = fmaf(atS[3], __builtin_fabsf(s), e2b);
            s = xrS[il][4] + wb.x; e2a = fmaf(atS[4], __builtin_fabsf(s), e2a);
            s = xrS[il][5] + wb.y; e2b = fmaf(atS[5], __builtin_fabsf(s), e2b);
            s = xrS[il][6] + wb.z; e2a = fmaf(atS[6], __builtin_fabsf(s), e2a);
            s = xrS[il][7] + wb.w; e2b = fmaf(atS[7], __builtin_fabsf(s), e2b);
            float eh = e2a + e2b;
            eh = dpp_add<0xB1>(eh);          // + lane^1 (quad_perm 1,0,3,2)
            eh = dpp_add<0x4E>(eh);          // + lane^2 (quad_perm 2,3,0,1)
            float e = (wd + drv[il]) + eh;   // full log2-domain logit
            bool keep = (wmv[il] != 0) || (j == i0 + il);
            float w = keep ? fast_exp2(e) : 0.f;
            sumw[il] += w;
            v2f ws = (v2f){w, w};
            pk_fma(acc[il][0], ws, p0);
            pk_fma(acc[il][1], ws, p1);
            pk_fma(acc[il][2], ws, p2);
            pk_fma(acc[il][3], ws, p3);
        }
    }

    // ---- epilogue: butterfly over js lane-bits (2-5); cq bits preserved ----
    #pragma unroll
    for (int m = 4; m <= 32; m <<= 1) {
        #pragma unroll
        for (int il = 0; il < TI; ++il) {
            sumw[il] += __shfl_xor(sumw[il], m);
            #pragma unroll
            for (int q = 0; q < 4; ++q) {
                acc[il][q].x += __shfl_xor(acc[il][q].x, m);
                acc[il][q].y += __shfl_xor(acc[il][q].y, m);
            }
        }
    }

    // writers: js-groups 0..7 each store one float4 (il = g>>1, half = g&1)
    const int g = js;
    if (g < 8) {
        const int il  = g >> 1;
        const int hf  = g & 1;
        const float inv = 1.f / sumw[il];
        const int c0 = cbase + hf * 4;
        float4 bq = *(const float4*)(bias + c0);
        v2f a0 = acc[il][2 * hf], a1 = acc[il][2 * hf + 1];
        float4 vout = make_float4(fmaf(a0.x, inv, bq.x),
                                  fmaf(a0.y, inv, bq.y),
                                  fmaf(a1.x, inv, bq.z),
                                  fmaf(a1.y, inv, bq.w));
        *(float4*)(&out[((size_t)(b * N_ + i0 + il)) * OD + c0]) = vout;
    }
}

extern "C" void kernel_launch(void* const* d_in, const int* in_sizes, int n_in,
                              void* d_out, int out_size, void* d_ws, size_t ws_size,
                              hipStream_t stream) {
    const float* x    = (const float*)d_in[0];
    const int*   adj  = (const int*)d_in[1];
    const float* Wl   = (const float*)d_in[2];
    const float* bl   = (const float*)d_in[3];
    const float* Wr   = (const float*)d_in[4];
    const float* br   = (const float*)d_in[5];
    const float* att  = (const float*)d_in[6];
    const float* bias = (const float*)d_in[7];
    float* out = (float*)d_out;

    float* xl = (float*)d_ws;                    // 2 MB
    float* xr = xl + (size_t)B_ * N_ * OD;       // 2 MB
    float* dl = xr + (size_t)B_ * N_ * OD;       // 64 KB
    float* dr = dl + (size_t)B_ * N_ * H_;       // 64 KB

    proj_kernel<<<512, 512, 0, stream>>>(x, Wl, bl, Wr, br, att, xl, xr, dl, dr);
    attn_kernel<<<1024, 256, 0, stream>>>(adj, att, bias, xl, xr, dl, dr, out);
}

// Round 6
// 120.968 us; speedup vs baseline: 1.0564x; 1.0564x over previous
//
#include <hip/hip_runtime.h>

#define B_   8
#define N_   512
#define IND  256
#define H_   4
#define PH   32
#define OD   128   // H_*PH
#define TI   4     // targets per block (attn)

typedef float v2f __attribute__((ext_vector_type(2)));

// leaky 0.4 * log2(e), and 0.6 * log2(e): logits in log2 domain -> v_exp_f32.
#define ATT_SCALE 0.5770780163555854f
#define DLR_SCALE 0.8656170245333781f

template <int PAT>
__device__ __forceinline__ float dpp_add(float x) {
    int yi = __builtin_amdgcn_mov_dpp(__float_as_int(x), PAT, 0xF, 0xF, true);
    return x + __int_as_float(yi);
}

__device__ __forceinline__ float fast_exp2(float x) {
#if __has_builtin(__builtin_amdgcn_exp2f)
    return __builtin_amdgcn_exp2f(x);
#else
    return exp2f(x);
#endif
}

// Packed fp32 FMA: d += a*b on both halves, ONE VOP3P instruction.
__device__ __forceinline__ void pk_fma(v2f& d, v2f a, v2f b) {
    asm("v_pk_fma_f32 %0, %1, %2, %0" : "+v"(d) : "v"(a), "v"(b));
}

// ---------------------------------------------------------------------------
// Kernel 1 v7: xl = x@Wl + bl ; xr = x@Wr + br  plus pre-scaled rank-1 parts.
// r5 post-mortem: v2/v4/v6 all ~30us vs 3.7us issue floor -- latency-starved;
// v4 had LDS room for 4 blocks/CU but grid 512 supplied only 2; v6's 67.6KB
// LDS capped 2. v7: 4 rows/block, 256 thr, grid 1024 -> 4 blocks/CU supplied
// AND resident (LDS 21.5KB, VGPR ~50 < 64 -> 8 waves/SIMD allowed).
// W still read EXACTLY once per block (og32 x ks4 x which2 disjoint cover).
// Thread = 4 rows x 4 cols x 64k, chunk = 2k, parity 1-deep W prefetch.
// All 4 K-slices stage to padded LDS (stride 17: 17*og mod 32 bijective ->
// <=2-way banks, free); final read remapped so every thread writes one
// coalesced float4 row-segment.
// ---------------------------------------------------------------------------
__global__ __launch_bounds__(256, 4) void proj_kernel(
    const float* __restrict__ x,
    const float* __restrict__ Wl, const float* __restrict__ bl,
    const float* __restrict__ Wr, const float* __restrict__ br,
    const float* __restrict__ att,
    float* __restrict__ xl, float* __restrict__ xr,
    float* __restrict__ dl, float* __restrict__ dr)
{
    __shared__ float xs[4 * IND];        // 4 KB
    __shared__ float comb[4][64][17];    // 17408 B

    const int t = threadIdx.x;
    const int row0 = blockIdx.x * 4;

    ((float4*)xs)[t] = ((const float4*)(x + (size_t)row0 * IND))[t];
    __syncthreads();

    const int og    = t & 31;        // col quad: cols og*4 .. og*4+3
    const int ks    = (t >> 5) & 3;  // K slice: k0 = ks*64
    const int which = t >> 7;        // 0: Wl->xl/dl, 1: Wr->xr/dr
    const int o0 = og * 4;
    const int k0 = ks * 64;
    const float* W = (which ? Wr : Wl) + (size_t)k0 * OD + o0;

    float acc[4][4];
    #pragma unroll
    for (int r = 0; r < 4; ++r)
        #pragma unroll
        for (int c = 0; c < 4; ++c) acc[r][c] = 0.f;

    float4 wb[2][2];
    wb[0][0] = *(const float4*)(W);
    wb[0][1] = *(const float4*)(W + OD);

    #pragma unroll 2
    for (int s = 0; s < 32; ++s) {       // 32 chunks of 2 k (K=64 per thread)
        const int cur = s & 1, nxt = cur ^ 1;
        if (s < 31) {
            const float* Wq = W + (size_t)(2 * (s + 1)) * OD;
            wb[nxt][0] = *(const float4*)(Wq);
            wb[nxt][1] = *(const float4*)(Wq + OD);
        }
        #pragma unroll
        for (int r = 0; r < 4; ++r) {
            float2 xv = *(const float2*)(&xs[r * IND + k0 + 2 * s]);
            acc[r][0] = fmaf(xv.x, wb[cur][0].x, acc[r][0]);
            acc[r][1] = fmaf(xv.x, wb[cur][0].y, acc[r][1]);
            acc[r][2] = fmaf(xv.x, wb[cur][0].z, acc[r][2]);
            acc[r][3] = fmaf(xv.x, wb[cur][0].w, acc[r][3]);
            acc[r][0] = fmaf(xv.y, wb[cur][1].x, acc[r][0]);
            acc[r][1] = fmaf(xv.y, wb[cur][1].y, acc[r][1]);
            acc[r][2] = fmaf(xv.y, wb[cur][1].z, acc[r][2]);
            acc[r][3] = fmaf(xv.y, wb[cur][1].w, acc[r][3]);
        }
    }

    // stage ALL 4 K-slice partials (banks (17*og+i)%32: og-bijective, 2-way)
    const int pid = og | (which << 5);   // 0..63
    #pragma unroll
    for (int i = 0; i < 16; ++i)
        comb[ks][pid][i] = acc[i >> 2][i & 3];
    __syncthreads();

    // final: remap thread -> (og', row', which'); one float4 output each
    const int ogf = t & 31;
    const int rf  = (t >> 5) & 3;
    const int whf = t >> 7;
    const int pidf = ogf | (whf << 5);
    const float* bb = whf ? br : bl;
    float* dst = whf ? xr : xl;
    float* dp  = whf ? dr : dl;
    float4 bv = *(const float4*)(bb + ogf * 4);
    float4 av = *(const float4*)(att + ogf * 4);
    const float bvf[4] = {bv.x, bv.y, bv.z, bv.w};
    const float avf[4] = {av.x, av.y, av.z, av.w};
    float y[4];
    #pragma unroll
    for (int c = 0; c < 4; ++c) {
        const int idx = rf * 4 + c;
        y[c] = ((comb[0][pidf][idx] + comb[1][pidf][idx])
              + (comb[2][pidf][idx] + comb[3][pidf][idx])) + bvf[c];
    }
    *(float4*)(&dst[(size_t)(row0 + rf) * OD + ogf * 4]) =
        make_float4(y[0], y[1], y[2], y[3]);
    // rank-1 part: dl/dr[n,h] = 0.6*log2e * sum_c att[h,c]*y[c]
    float dc = fmaf(avf[0], y[0], fmaf(avf[1], y[1],
               fmaf(avf[2], y[2], avf[3] * y[3])));
    dc += __shfl_xor(dc, 1);
    dc += __shfl_xor(dc, 2);
    dc += __shfl_xor(dc, 4);   // sums the 8 og-lanes of one head
    if ((ogf & 7) == 0)
        dp[(size_t)(row0 + rf) * H_ + (ogf >> 3)] = DLR_SCALE * dc;
}

// ---------------------------------------------------------------------------
// Kernel 2 v7: masked-softmax attention aggregate.
// r5 post-mortem: with TI=4 the wave supply is work-limited at 16 waves/CU
// (1024 blocks x 4 waves); the fix is j-split INSIDE the block: 512-thread
// blocks, js = 32 j-slices, u-loop 16 -> 4 blocks/CU x 8 waves = 32 waves/CU,
// no combine kernel (js-reduction stays in-block).
// Algebraic cut: drv[il] scales every w of target il by exp2(drv) -> cancels
// exactly between softmax numerator and denominator. DROPPED (-4 VGPR,
// -1 load -4 add per u) -> working set ~64 fits (512,4)'s cap=64.
// r4's proven pieces kept: TI=4, manual 1-deep pipeline, XCD<->batch swizzle
// (FETCH 42->6 MB), conflict-free LDS epilogue (now 2 il-passes, 33.8 KB).
// ---------------------------------------------------------------------------
__global__ __launch_bounds__(512, 4) void attn_kernel(
    const int* __restrict__ adj, const float* __restrict__ att,
    const float* __restrict__ bias,
    const float* __restrict__ xl, const float* __restrict__ xr,
    const float* __restrict__ dl, const float* __restrict__ dr,
    float* __restrict__ out)
{
    __shared__ float sacc[H_][2][32][PH + 1];  // 33792 B (two il per pass)
    __shared__ float ssum[H_][32][TI];         // 2 KB

    const int t = threadIdx.x;
    const int bid = (blockIdx.x & 7) * 128 + (blockIdx.x >> 3);
    const int b  = bid >> 7;
    const int i0 = (bid & 127) * TI;
    const int cq = t & 3;
    const int js = (t >> 2) & 31;   // 32 j-slices
    const int h  = t >> 7;
    const int cbase = h * PH + cq * 8;

    // preload att (pre-scaled by 0.4*log2e) and xr fragments for all 4 targets
    float atS[8];
    {
        const float* ap = att + cbase;
        float4 a0 = *(const float4*)(ap);
        float4 a1 = *(const float4*)(ap + 4);
        atS[0] = ATT_SCALE * a0.x; atS[1] = ATT_SCALE * a0.y;
        atS[2] = ATT_SCALE * a0.z; atS[3] = ATT_SCALE * a0.w;
        atS[4] = ATT_SCALE * a1.x; atS[5] = ATT_SCALE * a1.y;
        atS[6] = ATT_SCALE * a1.z; atS[7] = ATT_SCALE * a1.w;
    }
    float xrS[TI][8];
    #pragma unroll
    for (int il = 0; il < TI; ++il) {
        const float* xp = xr + ((size_t)(b * N_ + i0 + il)) * OD + cbase;
        float4 r0 = *(const float4*)(xp);
        float4 r1 = *(const float4*)(xp + 4);
        xrS[il][0] = r0.x; xrS[il][1] = r0.y; xrS[il][2] = r0.z; xrS[il][3] = r0.w;
        xrS[il][4] = r1.x; xrS[il][5] = r1.y; xrS[il][6] = r1.z; xrS[il][7] = r1.w;
    }

    v2f acc[TI][4];
    float sumw[TI];
    #pragma unroll
    for (int il = 0; il < TI; ++il) {
        sumw[il] = 0.f;
        #pragma unroll
        for (int m = 0; m < 4; ++m) acc[il][m] = (v2f){0.f, 0.f};
    }

    // software-pipelined j-loop: j = u*32 + js, u = 0..15
    const float* xlp = xl + ((size_t)(b * N_ + js)) * OD + cbase;
    const int*   ajp = adj + ((size_t)(b * N_ + js)) * N_ + i0;
    const float* dlp = dl + ((size_t)(b * N_ + js)) * H_ + h;

    float4 va = *(const float4*)(xlp);
    float4 vb = *(const float4*)(xlp + 4);
    int4   mj = *(const int4*)(ajp);
    float  dj = *dlp;

    #pragma unroll 2
    for (int u = 0; u < 16; ++u) {
        float4 wa = va, wb = vb;
        int4   wm = mj;
        float  wd = dj;
        if (u < 15) {
            xlp += 32 * OD; ajp += 32 * N_; dlp += 32 * H_;
            va = *(const float4*)(xlp);
            vb = *(const float4*)(xlp + 4);
            mj = *(const int4*)(ajp);
            dj = *dlp;
        }
        const int j = u * 32 + js;
        v2f p0 = (v2f){wa.x, wa.y}, p1 = (v2f){wa.z, wa.w};
        v2f p2 = (v2f){wb.x, wb.y}, p3 = (v2f){wb.z, wb.w};
        int wmv[TI] = {wm.x, wm.y, wm.z, wm.w};
        #pragma unroll
        for (int il = 0; il < TI; ++il) {
            float s, e2a = 0.f, e2b = 0.f;
            s = xrS[il][0] + wa.x; e2a = fmaf(atS[0], __builtin_fabsf(s), e2a);
            s = xrS[il][1] + wa.y; e2b = fmaf(atS[1], __builtin_fabsf(s), e2b);
            s = xrS[il][2] + wa.z; e2a = fmaf(atS[2], __builtin_fabsf(s), e2a);
            s = xrS[il][3] + wa.w; e2b = fmaf(atS[3], __builtin_fabsf(s), e2b);
            s = xrS[il][4] + wb.x; e2a = fmaf(atS[4], __builtin_fabsf(s), e2a);
            s = xrS[il][5] + wb.y; e2b = fmaf(atS[5], __builtin_fabsf(s), e2b);
            s = xrS[il][6] + wb.z; e2a = fmaf(atS[6], __builtin_fabsf(s), e2a);
            s = xrS[il][7] + wb.w; e2b = fmaf(atS[7], __builtin_fabsf(s), e2b);
            float eh = e2a + e2b;
            eh = dpp_add<0xB1>(eh);          // + lane^1 (quad_perm 1,0,3,2)
            eh = dpp_add<0x4E>(eh);          // + lane^2 (quad_perm 2,3,0,1)
            float e = wd + eh;               // log2 logit (drv cancels in softmax)
            bool keep = (wmv[il] != 0) || (j == i0 + il);
            float w = keep ? fast_exp2(e) : 0.f;
            sumw[il] += w;
            v2f ws = (v2f){w, w};
            pk_fma(acc[il][0], ws, p0);
            pk_fma(acc[il][1], ws, p1);
            pk_fma(acc[il][2], ws, p2);
            pk_fma(acc[il][3], ws, p3);
        }
    }

    // ---- epilogue: two il-passes through LDS; reduce over the 32 js ----
    if (cq == 0) {
        #pragma unroll
        for (int il = 0; il < TI; ++il)
            ssum[h][js][il] = sumw[il];
    }
    // pass 0: il 0,1   (write banks (js+8cq)%32: exactly 2-way, free)
    #pragma unroll
    for (int p = 0; p < 2; ++p) {
        *(float4*)(&sacc[h][p][js][cq * 8]) =
            make_float4(acc[p][0].x, acc[p][0].y, acc[p][1].x, acc[p][1].y);
        *(float4*)(&sacc[h][p][js][cq * 8 + 4]) =
            make_float4(acc[p][2].x, acc[p][2].y, acc[p][3].x, acc[p][3].y);
    }
    __syncthreads();
    if (t < 256) {
        const int c   = t & 31;
        const int ilr = (t >> 5) & 1;
        const int hr  = t >> 6;
        float a = 0.f, st = 0.f;
        #pragma unroll
        for (int k = 0; k < 32; ++k) {
            a  += sacc[hr][ilr][k][c];       // banks (k+c)%32: conflict-free
            st += ssum[hr][k][ilr];
        }
        const int cg = hr * PH + c;
        out[((size_t)(b * N_ + i0 + ilr)) * OD + cg] =
            fmaf(a, 1.f / st, bias[cg]);
    }
    __syncthreads();
    // pass 1: il 2,3
    #pragma unroll
    for (int p = 0; p < 2; ++p) {
        *(float4*)(&sacc[h][p][js][cq * 8]) =
            make_float4(acc[2 + p][0].x, acc[2 + p][0].y,
                        acc[2 + p][1].x, acc[2 + p][1].y);
        *(float4*)(&sacc[h][p][js][cq * 8 + 4]) =
            make_float4(acc[2 + p][2].x, acc[2 + p][2].y,
                        acc[2 + p][3].x, acc[2 + p][3].y);
    }
    __syncthreads();
    if (t < 256) {
        const int c   = t & 31;
        const int ilr = (t >> 5) & 1;
        const int hr  = t >> 6;
        float a = 0.f, st = 0.f;
        #pragma unroll
        for (int k = 0; k < 32; ++k) {
            a  += sacc[hr][ilr][k][c];
            st += ssum[hr][k][2 + ilr];
        }
        const int cg = hr * PH + c;
        out[((size_t)(b * N_ + i0 + 2 + ilr)) * OD + cg] =
            fmaf(a, 1.f / st, bias[cg]);
    }
}

extern "C" void kernel_launch(void* const* d_in, const int* in_sizes, int n_in,
                              void* d_out, int out_size, void* d_ws, size_t ws_size,
                              hipStream_t stream) {
    const float* x    = (const float*)d_in[0];
    const int*   adj  = (const int*)d_in[1];
    const float* Wl   = (const float*)d_in[2];
    const float* bl   = (const float*)d_in[3];
    const float* Wr   = (const float*)d_in[4];
    const float* br   = (const float*)d_in[5];
    const float* att  = (const float*)d_in[6];
    const float* bias = (const float*)d_in[7];
    float* out = (float*)d_out;

    float* xl = (float*)d_ws;                    // 2 MB
    float* xr = xl + (size_t)B_ * N_ * OD;       // 2 MB
    float* dl = xr + (size_t)B_ * N_ * OD;       // 64 KB
    float* dr = dl + (size_t)B_ * N_ * H_;       // 64 KB

    proj_kernel<<<1024, 256, 0, stream>>>(x, Wl, bl, Wr, br, att, xl, xr, dl, dr);
    attn_kernel<<<1024, 512, 0, stream>>>(adj, att, bias, xl, xr, dl, dr, out);
}